// Round 26
// baseline (34.605 us; speedup 1.0000x reference)
//
#include <hip/hip_runtime.h>

#define B_  4
#define NQ_ 256
#define NK_ 512
#define H_  256
#define PADK 520   // half8s per E row: stride 8320B, breaks 8KB aliasing

typedef _Float16 half8  __attribute__((ext_vector_type(8)));
typedef _Float16 half4_t __attribute__((ext_vector_type(4)));

// 2*log2(e): exp2(x*TWO_LOG2E) = e^{2x}
#define TWO_LOG2E 2.8853900817779268f

// SPLIT-K2 gemm (r25, best known): 192 tiles, 512 threads/block; warp-group
// g = tid>>8 computes K-half [g*128,+128) in its own LDS stage buffers ->
// 2 waves/SIMD so one group's VALU overlaps the other's LDS/VMEM phases.
__global__ __launch_bounds__(512)
void gemm_fused(const float* __restrict__ xq, const float* __restrict__ xk,
                const float* __restrict__ w1, const float* __restrict__ w2,
                _Float16* __restrict__ Ebuf,  // [B][32][PADK][8] halves
                float* __restrict__ Fbuf)     // [B][NQ][H]
{
    constexpr int BK = 32;
    const float* A; const float* Bm;
    int m0, n0, bz; bool iskt;
    {
        int id = blockIdx.x;
        if (id < 128) {                      // kt: M=H(o), N=NK(k)
            iskt = true;
            bz = id >> 5; int t = id & 31;
            m0 = (t >> 3) * 64; n0 = (t & 7) * 64;
            A = w1; Bm = xk + (long)bz * NK_ * H_;
        } else {                             // qt: M=NQ(q), N=H(o)
            iskt = false;
            id -= 128;
            bz = id >> 4; int t = id & 15;
            m0 = (t >> 2) * 64; n0 = (t & 3) * 64;
            A = xq + (long)bz * NQ_ * H_; Bm = w2;
        }
    }
    const int lda = H_, ldb = H_;
    const int ks = (blockIdx.x & 7) * BK;    // per-block K stagger (r22 win)

    __shared__ float As[2][BK][68];
    __shared__ float Bs[2][BK][68];
    __shared__ float Cred[16][260];          // grp1 partials; col/thread

    const int tid  = threadIdx.x & 255;
    const int grp  = threadIdx.x >> 8;       // K-half owner
    const int kofs = grp * 128;
    const int lrow = tid >> 2;
    const int lk   = (tid & 3) * 8;
    const int tm   = (tid >> 4) * 4;
    const int tn   = (tid & 15) * 4;

    float acc[4][4] = {};

    int kt0 = (ks + kofs) & (H_ - 1);
    float4 a0_r = *(const float4*)&A [(long)(m0 + lrow) * lda + kt0 + lk];
    float4 a1_r = *(const float4*)&A [(long)(m0 + lrow) * lda + kt0 + lk + 4];
    float4 b0_r = *(const float4*)&Bm[(long)(n0 + lrow) * ldb + kt0 + lk];
    float4 b1_r = *(const float4*)&Bm[(long)(n0 + lrow) * ldb + kt0 + lk + 4];
    float4 a0_n = a0_r, a1_n = a1_r, b0_n = b0_r, b1_n = b1_r;

    for (int t = 0; t < 128; t += BK) {      // 4 iters per group
        __syncthreads();
        As[grp][lk+0][lrow]=a0_r.x; As[grp][lk+1][lrow]=a0_r.y;
        As[grp][lk+2][lrow]=a0_r.z; As[grp][lk+3][lrow]=a0_r.w;
        As[grp][lk+4][lrow]=a1_r.x; As[grp][lk+5][lrow]=a1_r.y;
        As[grp][lk+6][lrow]=a1_r.z; As[grp][lk+7][lrow]=a1_r.w;
        Bs[grp][lk+0][lrow]=b0_r.x; Bs[grp][lk+1][lrow]=b0_r.y;
        Bs[grp][lk+2][lrow]=b0_r.z; Bs[grp][lk+3][lrow]=b0_r.w;
        Bs[grp][lk+4][lrow]=b1_r.x; Bs[grp][lk+5][lrow]=b1_r.y;
        Bs[grp][lk+6][lrow]=b1_r.z; Bs[grp][lk+7][lrow]=b1_r.w;
        if (t + BK < 128) {
            const int ktn = (ks + kofs + t + BK) & (H_ - 1);
            a0_n = *(const float4*)&A [(long)(m0 + lrow) * lda + ktn + lk];
            a1_n = *(const float4*)&A [(long)(m0 + lrow) * lda + ktn + lk + 4];
            b0_n = *(const float4*)&Bm[(long)(n0 + lrow) * ldb + ktn + lk];
            b1_n = *(const float4*)&Bm[(long)(n0 + lrow) * ldb + ktn + lk + 4];
        }
        __syncthreads();
        #pragma unroll
        for (int kk = 0; kk < BK; ++kk) {
            float4 av = *(const float4*)&As[grp][kk][tm];
            float4 bv = *(const float4*)&Bs[grp][kk][tn];
            float am[4] = {av.x, av.y, av.z, av.w};
            float bn[4] = {bv.x, bv.y, bv.z, bv.w};
            #pragma unroll
            for (int i = 0; i < 4; ++i)
                #pragma unroll
                for (int j = 0; j < 4; ++j)
                    acc[i][j] = fmaf(am[i], bn[j], acc[i][j]);
        }
        a0_r = a0_n; a1_r = a1_n; b0_r = b0_n; b1_r = b1_n;
    }

    // combine K-halves: grp1 -> LDS -> grp0
    __syncthreads();
    if (grp == 1) {
        #pragma unroll
        for (int i = 0; i < 4; ++i)
            #pragma unroll
            for (int j = 0; j < 4; ++j)
                Cred[i * 4 + j][tid] = acc[i][j];
    }
    __syncthreads();
    if (grp == 0) {
        #pragma unroll
        for (int i = 0; i < 4; ++i)
            #pragma unroll
            for (int j = 0; j < 4; ++j)
                acc[i][j] += Cred[i * 4 + j][tid];

        if (iskt) {
            const long gbase = ((long)bz * 32 + ((m0 + tm) >> 3)) * PADK * 8 + (tm & 7);
            #pragma unroll
            for (int j = 0; j < 4; ++j) {
                half4_t h4;
                #pragma unroll
                for (int i = 0; i < 4; ++i) {
                    float e = __builtin_amdgcn_exp2f(acc[i][j] * TWO_LOG2E);
                    h4[i] = (_Float16)fminf(e, 60000.0f);
                }
                *(half4_t*)&Ebuf[gbase + (long)(n0 + tn + j) * 8] = h4;
            }
        } else {
            #pragma unroll
            for (int i = 0; i < 4; ++i) {
                float4 f4v = { __builtin_amdgcn_exp2f(acc[i][0] * TWO_LOG2E),
                               __builtin_amdgcn_exp2f(acc[i][1] * TWO_LOG2E),
                               __builtin_amdgcn_exp2f(acc[i][2] * TWO_LOG2E),
                               __builtin_amdgcn_exp2f(acc[i][3] * TWO_LOG2E) };
                *(float4*)&Fbuf[((long)bz * NQ_ + m0 + tm + i) * H_ + n0 + tn] = f4v;
            }
        }
    }
}

// attn (r25 math) with FULLY UNROLLED 32-row loop:
//  - F/v scalar operands prefetched 2 rows ahead (~224 cyc > s-cache latency;
//    r16's null used ~56 cyc distance) into a 3-set rotation, all indices
//    unroll-constant (rule #20: static indexing -> registers).
//  - E rows prefetched 6 rows ahead into an 8-slot rotating window.
// Targets the ~6us of stall measured in the loop (12.6us vs 6.2us issue model).
__global__ __launch_bounds__(512, 2)
void attn_main(const half8* __restrict__ Eh,   // [B][32][PADK]
               const float* __restrict__ Fbuf, // [B][NQ][H]
               const float* __restrict__ v,    // [H]
               float* __restrict__ out)        // [B][NQ][NK]
{
    const int k = threadIdx.x, b = blockIdx.y, q0 = blockIdx.x * 2;
    const int sb = (blockIdx.x & 7) * 4;       // staggered row-group start

    const half8* kp   = Eh + (long)b * 32 * PADK + k;
    const float4* F0p = (const float4*)(Fbuf + ((long)b * NQ_ + q0) * H_);
    const float4* F1p = F0p + (H_ / 4);
    const float4* v4p = (const float4*)v;

    float T0 = 0.f, T1 = 0.f;

    // E window: 8 slots, rows sb..sb+5 preloaded; slot i%8 holds row sb+i.
    half8 EW[8];
    #pragma unroll
    for (int i = 0; i < 6; ++i) EW[i] = kp[(long)((sb + i) & 31) * PADK];

    // F/v sets: 3-deep rotation, set i%3 holds row sb+i's operands.
    float4 Sva[3], Svb[3], Sf0a[3], Sf0b[3], Sf1a[3], Sf1b[3];
    #pragma unroll
    for (int i = 0; i < 2; ++i) {
        const int r = (sb + i) & 31;
        Sva[i]  = v4p[2*r];  Svb[i]  = v4p[2*r+1];
        Sf0a[i] = F0p[2*r];  Sf0b[i] = F0p[2*r+1];
        Sf1a[i] = F1p[2*r];  Sf1b[i] = F1p[2*r+1];
    }

#define QTERM(T, E0, E1, E2, E3, FQ, VV)                                      \
    {                                                                         \
        float d0 = fmaf(E0, FQ.x, 1.f), d1 = fmaf(E1, FQ.y, 1.f);             \
        float d2 = fmaf(E2, FQ.z, 1.f), d3 = fmaf(E3, FQ.w, 1.f);             \
        float D01 = d0 * d1, D23 = d2 * d3;                                   \
        float N01 = fmaf(VV.x, d1, VV.y * d0);                                \
        float N23 = fmaf(VV.z, d3, VV.w * d2);                                \
        float N   = fmaf(N01, D23, N23 * D01);                                \
        T = fmaf(N, __builtin_amdgcn_rcpf(D01 * D23), T);                     \
    }

    #pragma unroll
    for (int i = 0; i < 32; ++i) {
        // prefetch F/v for row i+2 into set (i+2)%3 (wrap-harmless)
        {
            const int rl = (sb + i + 2) & 31;
            const int s  = (i + 2) % 3;
            Sva[s]  = v4p[2*rl];  Svb[s]  = v4p[2*rl+1];
            Sf0a[s] = F0p[2*rl];  Sf0b[s] = F0p[2*rl+1];
            Sf1a[s] = F1p[2*rl];  Sf1b[s] = F1p[2*rl+1];
        }
        // prefetch E for row i+6 into slot (i+6)%8 (wrap-harmless)
        EW[(i + 6) & 7] = kp[(long)((sb + i + 6) & 31) * PADK];

        // compute row sb+i with E slot i%8 and F set i%3
        const half8 KV = EW[i & 7];
        const int s = i % 3;
        float e0 = (float)KV[0], e1 = (float)KV[1], e2 = (float)KV[2],
              e3 = (float)KV[3], e4 = (float)KV[4], e5 = (float)KV[5],
              e6 = (float)KV[6], e7 = (float)KV[7];
        QTERM(T0, e0, e1, e2, e3, Sf0a[s], Sva[s])
        QTERM(T0, e4, e5, e6, e7, Sf0b[s], Svb[s])
        QTERM(T1, e0, e1, e2, e3, Sf1a[s], Sva[s])
        QTERM(T1, e4, e5, e6, e7, Sf1b[s], Svb[s])
    }
#undef QTERM

    float val0 = -2.f * T0;
    float val1 = -2.f * T1;

    // ---- log-softmax over k, no max pass (|val| <= 2*sum|v| ~ 16, safe) ----
    __shared__ float red[8][2];
    const int lane = k & 63, wv = k >> 6;

    float e0 = __builtin_amdgcn_exp2f(val0 * 1.4426950408889634f);
    float e1 = __builtin_amdgcn_exp2f(val1 * 1.4426950408889634f);
    #pragma unroll
    for (int o = 32; o; o >>= 1) {
        e0 += __shfl_xor(e0, o, 64);
        e1 += __shfl_xor(e1, o, 64);
    }
    if (lane == 0) { red[wv][0] = e0; red[wv][1] = e1; }
    __syncthreads();
    float s0 = 0.f, s1 = 0.f;
    #pragma unroll
    for (int w = 0; w < 8; ++w) { s0 += red[w][0]; s1 += red[w][1]; }

    float l0 = __builtin_amdgcn_logf(s0) * 0.6931471805599453f;
    float l1 = __builtin_amdgcn_logf(s1) * 0.6931471805599453f;
    out[((long)b * NQ_ + q0 + 0) * NK_ + k] = val0 - l0;
    out[((long)b * NQ_ + q0 + 1) * NK_ + k] = val1 - l1;
}

extern "C" void kernel_launch(void* const* d_in, const int* in_sizes, int n_in,
                              void* d_out, int out_size, void* d_ws, size_t ws_size,
                              hipStream_t stream)
{
    const float* xq = (const float*)d_in[0];  // (4,256,256)
    const float* xk = (const float*)d_in[1];  // (4,512,256)
    const float* w1 = (const float*)d_in[2];  // (256,256) out,in
    const float* w2 = (const float*)d_in[3];  // (256,256)
    const float* v  = (const float*)d_in[4];  // (1,256)
    float* out = (float*)d_out;

    _Float16* Ebuf = (_Float16*)d_ws;                     // ~1.06MB fp16
    float* Fbuf = (float*)((char*)d_ws + (size_t)B_ * 32 * PADK * 8 * 2);  // 1MB f32

    gemm_fused<<<dim3(192), 512, 0, stream>>>(xq, xk, w1, w2, Ebuf, Fbuf);
    attn_main<<<dim3(NQ_ / 2, B_), 512, 0, stream>>>(
        (const half8*)Ebuf, Fbuf, v, out);
}

// Round 27
// 34.238 us; speedup vs baseline: 1.0107x; 1.0107x over previous
//
#include <hip/hip_runtime.h>

#define B_  4
#define NQ_ 256
#define NK_ 512
#define H_  256
#define PADK 520   // half8s per E row: stride 8320B, breaks 8KB aliasing

typedef _Float16 half8  __attribute__((ext_vector_type(8)));
typedef _Float16 half4_t __attribute__((ext_vector_type(4)));

// 2*log2(e): exp2(x*TWO_LOG2E) = e^{2x}
#define TWO_LOG2E 2.8853900817779268f

// gemm = 32x64 tiles (384 blocks, r14's fastest tiling) x SPLIT-K2 (512
// threads; warp-group g = tid>>8 owns K-half) -> 12 waves/CU, 4x r25's
// wave count. Both levers individually verified (r14: ~10us; r25: -2.1us).
__global__ __launch_bounds__(512)
void gemm_fused(const float* __restrict__ xq, const float* __restrict__ xk,
                const float* __restrict__ w1, const float* __restrict__ w2,
                _Float16* __restrict__ Ebuf,  // [B][32][PADK][8] halves
                float* __restrict__ Fbuf)     // [B][NQ][H]
{
    constexpr int BK = 32;
    const float* A; const float* Bm;
    int m0, n0, bz; bool iskt;
    {
        int id = blockIdx.x;
        if (id < 256) {                      // kt: M=H(o) 8x32, N=NK(k) 8x64
            iskt = true;
            bz = id >> 6; int t = id & 63;
            m0 = (t >> 3) * 32; n0 = (t & 7) * 64;
            A = w1; Bm = xk + (long)bz * NK_ * H_;
        } else {                             // qt: M=NQ(q) 8x32, N=H(o) 4x64
            iskt = false;
            id -= 256;
            bz = id >> 5; int t = id & 31;
            m0 = (t >> 2) * 32; n0 = (t & 3) * 64;
            A = xq + (long)bz * NQ_ * H_; Bm = w2;
        }
    }
    const int lda = H_, ldb = H_;
    const int ks = (blockIdx.x & 7) * BK;    // per-block K stagger (r22 win)

    __shared__ float As[2][BK][36];
    __shared__ float Bs[2][BK][68];
    __shared__ float Cred[8][260];           // grp1 partials; col/thread

    const int tid  = threadIdx.x & 255;
    const int grp  = threadIdx.x >> 8;       // K-half owner
    const int kofs = grp * 128;
    const int arow = tid >> 3, ak = (tid & 7) * 4;   // A: 32m x 32k
    const int brow = tid >> 2, bk = (tid & 3) * 8;   // B: 64n x 32k
    const int tm = (tid >> 5) * 4;       // 0..28
    const int tn = (tid & 31) * 2;       // 0..62

    float acc[4][2] = {};

    int kt0 = (ks + kofs) & (H_ - 1);
    float4 a_r  = *(const float4*)&A [(long)(m0 + arow) * lda + kt0 + ak];
    float4 b0_r = *(const float4*)&Bm[(long)(n0 + brow) * ldb + kt0 + bk];
    float4 b1_r = *(const float4*)&Bm[(long)(n0 + brow) * ldb + kt0 + bk + 4];
    float4 a_n = a_r, b0_n = b0_r, b1_n = b1_r;

    for (int t = 0; t < 128; t += BK) {      // 4 iters per group
        __syncthreads();
        As[grp][ak+0][arow]=a_r.x; As[grp][ak+1][arow]=a_r.y;
        As[grp][ak+2][arow]=a_r.z; As[grp][ak+3][arow]=a_r.w;
        Bs[grp][bk+0][brow]=b0_r.x; Bs[grp][bk+1][brow]=b0_r.y;
        Bs[grp][bk+2][brow]=b0_r.z; Bs[grp][bk+3][brow]=b0_r.w;
        Bs[grp][bk+4][brow]=b1_r.x; Bs[grp][bk+5][brow]=b1_r.y;
        Bs[grp][bk+6][brow]=b1_r.z; Bs[grp][bk+7][brow]=b1_r.w;
        if (t + BK < 128) {
            const int ktn = (ks + kofs + t + BK) & (H_ - 1);
            a_n  = *(const float4*)&A [(long)(m0 + arow) * lda + ktn + ak];
            b0_n = *(const float4*)&Bm[(long)(n0 + brow) * ldb + ktn + bk];
            b1_n = *(const float4*)&Bm[(long)(n0 + brow) * ldb + ktn + bk + 4];
        }
        __syncthreads();
        #pragma unroll
        for (int kk = 0; kk < BK; ++kk) {
            float4 av = *(const float4*)&As[grp][kk][tm];
            float2 bv = *(const float2*)&Bs[grp][kk][tn];
            float am[4] = {av.x, av.y, av.z, av.w};
            #pragma unroll
            for (int i = 0; i < 4; ++i) {
                acc[i][0] = fmaf(am[i], bv.x, acc[i][0]);
                acc[i][1] = fmaf(am[i], bv.y, acc[i][1]);
            }
        }
        a_r = a_n; b0_r = b0_n; b1_r = b1_n;
    }

    // combine K-halves: grp1 -> LDS -> grp0
    __syncthreads();
    if (grp == 1) {
        #pragma unroll
        for (int i = 0; i < 4; ++i)
            #pragma unroll
            for (int j = 0; j < 2; ++j)
                Cred[i * 2 + j][tid] = acc[i][j];
    }
    __syncthreads();
    if (grp == 0) {
        #pragma unroll
        for (int i = 0; i < 4; ++i)
            #pragma unroll
            for (int j = 0; j < 2; ++j)
                acc[i][j] += Cred[i * 2 + j][tid];

        if (iskt) {
            const long gbase = ((long)bz * 32 + ((m0 + tm) >> 3)) * PADK * 8
                               + ((m0 + tm) & 7);
            #pragma unroll
            for (int j = 0; j < 2; ++j) {
                half4_t h4;
                #pragma unroll
                for (int i = 0; i < 4; ++i) {
                    float e = __builtin_amdgcn_exp2f(acc[i][j] * TWO_LOG2E);
                    h4[i] = (_Float16)fminf(e, 60000.0f);
                }
                *(half4_t*)&Ebuf[gbase + (long)(n0 + tn + j) * 8] = h4;
            }
        } else {
            #pragma unroll
            for (int i = 0; i < 4; ++i) {
                float2 f2v = { __builtin_amdgcn_exp2f(acc[i][0] * TWO_LOG2E),
                               __builtin_amdgcn_exp2f(acc[i][1] * TWO_LOG2E) };
                *(float2*)&Fbuf[((long)bz * NQ_ + m0 + tm + i) * H_ + n0 + tn] = f2v;
            }
        }
    }
}

// r25 attn (best measured, 32.34 total): QPB=2, fp16 E half8, SGPR F/v,
// stagger, rotating 4-row E window. (r26's deep unroll regressed: I-cache.)
__global__ __launch_bounds__(512, 2)
void attn_main(const half8* __restrict__ Eh,   // [B][32][PADK]
               const float* __restrict__ Fbuf, // [B][NQ][H]
               const float* __restrict__ v,    // [H]
               float* __restrict__ out)        // [B][NQ][NK]
{
    const int k = threadIdx.x, b = blockIdx.y, q0 = blockIdx.x * 2;
    const int sb = (blockIdx.x & 7) * 4;       // staggered row-group start

    const half8* kp   = Eh + (long)b * 32 * PADK + k;
    const float4* F0p = (const float4*)(Fbuf + ((long)b * NQ_ + q0) * H_);
    const float4* F1p = F0p + (H_ / 4);
    const float4* v4p = (const float4*)v;

    float T0 = 0.f, T1 = 0.f;

    half8 ka0 = kp[(long)(sb + 0) * PADK], ka1 = kp[(long)(sb + 1) * PADK],
          ka2 = kp[(long)(sb + 2) * PADK], ka3 = kp[(long)(sb + 3) * PADK];
    half8 kn0 = ka0, kn1 = ka1, kn2 = ka2, kn3 = ka3;

#define QTERM(T, E0, E1, E2, E3, FQ, VV)                                      \
    {                                                                         \
        float d0 = fmaf(E0, FQ.x, 1.f), d1 = fmaf(E1, FQ.y, 1.f);             \
        float d2 = fmaf(E2, FQ.z, 1.f), d3 = fmaf(E3, FQ.w, 1.f);             \
        float D01 = d0 * d1, D23 = d2 * d3;                                   \
        float N01 = fmaf(VV.x, d1, VV.y * d0);                                \
        float N23 = fmaf(VV.z, d3, VV.w * d2);                                \
        float N   = fmaf(N01, D23, N23 * D01);                                \
        T = fmaf(N, __builtin_amdgcn_rcpf(D01 * D23), T);                     \
    }
#define PROW(KV, R)                                                           \
    {                                                                         \
        float e0 = (float)KV[0], e1 = (float)KV[1], e2 = (float)KV[2],        \
              e3 = (float)KV[3], e4 = (float)KV[4], e5 = (float)KV[5],        \
              e6 = (float)KV[6], e7 = (float)KV[7];                           \
        float4 va  = v4p[2*(R)],   vb  = v4p[2*(R)+1];                        \
        float4 f0a = F0p[2*(R)],   f0b = F0p[2*(R)+1];                        \
        float4 f1a = F1p[2*(R)],   f1b = F1p[2*(R)+1];                        \
        QTERM(T0, e0, e1, e2, e3, f0a, va)                                    \
        QTERM(T0, e4, e5, e6, e7, f0b, vb)                                    \
        QTERM(T1, e0, e1, e2, e3, f1a, va)                                    \
        QTERM(T1, e4, e5, e6, e7, f1b, vb)                                    \
    }

    for (int gg = 0; gg < 32; gg += 4) {
        const int g = (gg + sb) & 31;          // rotated row-group
        if (gg + 4 < 32) {
            const int gn = (g + 4) & 31;
            kn0 = kp[(long)(gn + 0) * PADK];
            kn1 = kp[(long)(gn + 1) * PADK];
            kn2 = kp[(long)(gn + 2) * PADK];
            kn3 = kp[(long)(gn + 3) * PADK];
        }
        PROW(ka0, g + 0)
        PROW(ka1, g + 1)
        PROW(ka2, g + 2)
        PROW(ka3, g + 3)
        ka0 = kn0; ka1 = kn1; ka2 = kn2; ka3 = kn3;
    }
#undef PROW
#undef QTERM

    float val0 = -2.f * T0;
    float val1 = -2.f * T1;

    // ---- log-softmax over k, no max pass (|val| <= 2*sum|v| ~ 16, safe) ----
    __shared__ float red[8][2];
    const int lane = k & 63, wv = k >> 6;

    float e0 = __builtin_amdgcn_exp2f(val0 * 1.4426950408889634f);
    float e1 = __builtin_amdgcn_exp2f(val1 * 1.4426950408889634f);
    #pragma unroll
    for (int o = 32; o; o >>= 1) {
        e0 += __shfl_xor(e0, o, 64);
        e1 += __shfl_xor(e1, o, 64);
    }
    if (lane == 0) { red[wv][0] = e0; red[wv][1] = e1; }
    __syncthreads();
    float s0 = 0.f, s1 = 0.f;
    #pragma unroll
    for (int w = 0; w < 8; ++w) { s0 += red[w][0]; s1 += red[w][1]; }

    float l0 = __builtin_amdgcn_logf(s0) * 0.6931471805599453f;
    float l1 = __builtin_amdgcn_logf(s1) * 0.6931471805599453f;
    out[((long)b * NQ_ + q0 + 0) * NK_ + k] = val0 - l0;
    out[((long)b * NQ_ + q0 + 1) * NK_ + k] = val1 - l1;
}

extern "C" void kernel_launch(void* const* d_in, const int* in_sizes, int n_in,
                              void* d_out, int out_size, void* d_ws, size_t ws_size,
                              hipStream_t stream)
{
    const float* xq = (const float*)d_in[0];  // (4,256,256)
    const float* xk = (const float*)d_in[1];  // (4,512,256)
    const float* w1 = (const float*)d_in[2];  // (256,256) out,in
    const float* w2 = (const float*)d_in[3];  // (256,256)
    const float* v  = (const float*)d_in[4];  // (1,256)
    float* out = (float*)d_out;

    _Float16* Ebuf = (_Float16*)d_ws;                     // ~1.06MB fp16
    float* Fbuf = (float*)((char*)d_ws + (size_t)B_ * 32 * PADK * 8 * 2);  // 1MB f32

    gemm_fused<<<dim3(384), 512, 0, stream>>>(xq, xk, w1, w2, Ebuf, Fbuf);
    attn_main<<<dim3(NQ_ / 2, B_), 512, 0, stream>>>(
        (const half8*)Ebuf, Fbuf, v, out);
}

// Round 28
// 33.247 us; speedup vs baseline: 1.0409x; 1.0298x over previous
//
#include <hip/hip_runtime.h>

#define B_  4
#define NQ_ 256
#define NK_ 512
#define H_  256
#define PADK 520   // half8s per E row: stride 8320B, breaks 8KB aliasing

typedef _Float16 half8  __attribute__((ext_vector_type(8)));
typedef _Float16 half4_t __attribute__((ext_vector_type(4)));

// 2*log2(e): exp2(x*TWO_LOG2E) = e^{2x}
#define TWO_LOG2E 2.8853900817779268f

// SPLIT-K2 gemm (r25 base, best measured): 192 tiles, 512 threads; group
// g = tid>>8 owns K-half [g*128,+128). qt-epilogue now writes the PACKED
// per-(q-pair,row) operand records for attn: [f0a f0b f1a f1b va vb] (96B,
// contiguous) so attn's scalar loads merge into s_load_dwordx16+x8.
__global__ __launch_bounds__(512)
void gemm_fused(const float* __restrict__ xq, const float* __restrict__ xk,
                const float* __restrict__ w1, const float* __restrict__ w2,
                const float* __restrict__ v,
                _Float16* __restrict__ Ebuf,  // [B][32][PADK][8] halves
                float* __restrict__ Pack)     // [B][128 qp][32 row][24 f32]
{
    constexpr int BK = 32;
    const float* A; const float* Bm;
    int m0, n0, bz; bool iskt;
    {
        int id = blockIdx.x;
        if (id < 128) {                      // kt: M=H(o), N=NK(k)
            iskt = true;
            bz = id >> 5; int t = id & 31;
            m0 = (t >> 3) * 64; n0 = (t & 7) * 64;
            A = w1; Bm = xk + (long)bz * NK_ * H_;
        } else {                             // qt: M=NQ(q), N=H(o)
            iskt = false;
            id -= 128;
            bz = id >> 4; int t = id & 15;
            m0 = (t >> 2) * 64; n0 = (t & 3) * 64;
            A = xq + (long)bz * NQ_ * H_; Bm = w2;
        }
    }
    const int lda = H_, ldb = H_;
    const int ks = (blockIdx.x & 7) * BK;    // per-block K stagger (r22 win)

    __shared__ float As[2][BK][68];
    __shared__ float Bs[2][BK][68];
    __shared__ float Cred[16][260];          // grp1 partials; col/thread

    const int tid  = threadIdx.x & 255;
    const int grp  = threadIdx.x >> 8;       // K-half owner
    const int kofs = grp * 128;
    const int lrow = tid >> 2;
    const int lk   = (tid & 3) * 8;
    const int tm   = (tid >> 4) * 4;
    const int tn   = (tid & 15) * 4;

    float acc[4][4] = {};

    int kt0 = (ks + kofs) & (H_ - 1);
    float4 a0_r = *(const float4*)&A [(long)(m0 + lrow) * lda + kt0 + lk];
    float4 a1_r = *(const float4*)&A [(long)(m0 + lrow) * lda + kt0 + lk + 4];
    float4 b0_r = *(const float4*)&Bm[(long)(n0 + lrow) * ldb + kt0 + lk];
    float4 b1_r = *(const float4*)&Bm[(long)(n0 + lrow) * ldb + kt0 + lk + 4];
    float4 a0_n = a0_r, a1_n = a1_r, b0_n = b0_r, b1_n = b1_r;

    for (int t = 0; t < 128; t += BK) {      // 4 iters per group
        __syncthreads();
        As[grp][lk+0][lrow]=a0_r.x; As[grp][lk+1][lrow]=a0_r.y;
        As[grp][lk+2][lrow]=a0_r.z; As[grp][lk+3][lrow]=a0_r.w;
        As[grp][lk+4][lrow]=a1_r.x; As[grp][lk+5][lrow]=a1_r.y;
        As[grp][lk+6][lrow]=a1_r.z; As[grp][lk+7][lrow]=a1_r.w;
        Bs[grp][lk+0][lrow]=b0_r.x; Bs[grp][lk+1][lrow]=b0_r.y;
        Bs[grp][lk+2][lrow]=b0_r.z; Bs[grp][lk+3][lrow]=b0_r.w;
        Bs[grp][lk+4][lrow]=b1_r.x; Bs[grp][lk+5][lrow]=b1_r.y;
        Bs[grp][lk+6][lrow]=b1_r.z; Bs[grp][lk+7][lrow]=b1_r.w;
        if (t + BK < 128) {
            const int ktn = (ks + kofs + t + BK) & (H_ - 1);
            a0_n = *(const float4*)&A [(long)(m0 + lrow) * lda + ktn + lk];
            a1_n = *(const float4*)&A [(long)(m0 + lrow) * lda + ktn + lk + 4];
            b0_n = *(const float4*)&Bm[(long)(n0 + lrow) * ldb + ktn + lk];
            b1_n = *(const float4*)&Bm[(long)(n0 + lrow) * ldb + ktn + lk + 4];
        }
        __syncthreads();
        #pragma unroll
        for (int kk = 0; kk < BK; ++kk) {
            float4 av = *(const float4*)&As[grp][kk][tm];
            float4 bv = *(const float4*)&Bs[grp][kk][tn];
            float am[4] = {av.x, av.y, av.z, av.w};
            float bn[4] = {bv.x, bv.y, bv.z, bv.w};
            #pragma unroll
            for (int i = 0; i < 4; ++i)
                #pragma unroll
                for (int j = 0; j < 4; ++j)
                    acc[i][j] = fmaf(am[i], bn[j], acc[i][j]);
        }
        a0_r = a0_n; a1_r = a1_n; b0_r = b0_n; b1_r = b1_n;
    }

    // combine K-halves: grp1 -> LDS -> grp0
    __syncthreads();
    if (grp == 1) {
        #pragma unroll
        for (int i = 0; i < 4; ++i)
            #pragma unroll
            for (int j = 0; j < 4; ++j)
                Cred[i * 4 + j][tid] = acc[i][j];
    }
    __syncthreads();
    if (grp == 0) {
        #pragma unroll
        for (int i = 0; i < 4; ++i)
            #pragma unroll
            for (int j = 0; j < 4; ++j)
                acc[i][j] += Cred[i * 4 + j][tid];

        if (iskt) {
            const long gbase = ((long)bz * 32 + ((m0 + tm) >> 3)) * PADK * 8 + (tm & 7);
            #pragma unroll
            for (int j = 0; j < 4; ++j) {
                half4_t h4;
                #pragma unroll
                for (int i = 0; i < 4; ++i) {
                    float e = __builtin_amdgcn_exp2f(acc[i][j] * TWO_LOG2E);
                    h4[i] = (_Float16)fminf(e, 60000.0f);
                }
                *(half4_t*)&Ebuf[gbase + (long)(n0 + tn + j) * 8] = h4;
            }
        } else {
            // packed operand records: row = o-group of 8, bsel = which half
            const int row  = (n0 + tn) >> 3;
            const int bsel = ((n0 + tn) >> 2) & 1;
            const float4 v4 = *(const float4*)&v[n0 + tn];
            float4* Pb = (float4*)Pack + ((long)bz * 128) * 32 * 6;
            #pragma unroll
            for (int pi = 0; pi < 2; ++pi) {   // two q-pairs in this thread
                const int qp = ((m0 + tm) >> 1) + pi;
                float4* R4 = Pb + ((long)qp * 32 + row) * 6;
                float4 fe = { __builtin_amdgcn_exp2f(acc[2*pi+0][0] * TWO_LOG2E),
                              __builtin_amdgcn_exp2f(acc[2*pi+0][1] * TWO_LOG2E),
                              __builtin_amdgcn_exp2f(acc[2*pi+0][2] * TWO_LOG2E),
                              __builtin_amdgcn_exp2f(acc[2*pi+0][3] * TWO_LOG2E) };
                float4 fo = { __builtin_amdgcn_exp2f(acc[2*pi+1][0] * TWO_LOG2E),
                              __builtin_amdgcn_exp2f(acc[2*pi+1][1] * TWO_LOG2E),
                              __builtin_amdgcn_exp2f(acc[2*pi+1][2] * TWO_LOG2E),
                              __builtin_amdgcn_exp2f(acc[2*pi+1][3] * TWO_LOG2E) };
                R4[0 + bsel] = fe;    // f0{a|b}: even q of the pair
                R4[2 + bsel] = fo;    // f1{a|b}: odd q
                R4[4 + bsel] = v4;    // v{a|b}
            }
        }
    }
}

// attn (r25 math, QPB=2, fp16 E, stagger) with PACKED scalar operands:
// per PROW one contiguous 96B record -> s_load_dwordx16 + dwordx8 (2 SMEM
// ops, 1 wait) instead of 6 dwordx4 from 3 bases. Values bit-identical.
__global__ __launch_bounds__(512, 2)
void attn_main(const half8* __restrict__ Eh,   // [B][32][PADK]
               const float* __restrict__ Pack, // [B][128][32][24]
               float* __restrict__ out)        // [B][NQ][NK]
{
    const int k = threadIdx.x, b = blockIdx.y;
    const int qp = blockIdx.x;                 // q-pair index; q0 = 2*qp
    const int q0 = qp * 2;
    const int sb = (blockIdx.x & 7) * 4;       // staggered row-group start

    const half8* kp  = Eh + (long)b * 32 * PADK + k;
    const float4* Pp = (const float4*)Pack + ((long)(b * 128 + qp)) * 32 * 6;

    float T0 = 0.f, T1 = 0.f;

    half8 ka0 = kp[(long)(sb + 0) * PADK], ka1 = kp[(long)(sb + 1) * PADK],
          ka2 = kp[(long)(sb + 2) * PADK], ka3 = kp[(long)(sb + 3) * PADK];
    half8 kn0 = ka0, kn1 = ka1, kn2 = ka2, kn3 = ka3;

#define QTERM(T, E0, E1, E2, E3, FQ, VV)                                      \
    {                                                                         \
        float d0 = fmaf(E0, FQ.x, 1.f), d1 = fmaf(E1, FQ.y, 1.f);             \
        float d2 = fmaf(E2, FQ.z, 1.f), d3 = fmaf(E3, FQ.w, 1.f);             \
        float D01 = d0 * d1, D23 = d2 * d3;                                   \
        float N01 = fmaf(VV.x, d1, VV.y * d0);                                \
        float N23 = fmaf(VV.z, d3, VV.w * d2);                                \
        float N   = fmaf(N01, D23, N23 * D01);                                \
        T = fmaf(N, __builtin_amdgcn_rcpf(D01 * D23), T);                     \
    }
#define PROW(KV, R)                                                           \
    {                                                                         \
        float e0 = (float)KV[0], e1 = (float)KV[1], e2 = (float)KV[2],        \
              e3 = (float)KV[3], e4 = (float)KV[4], e5 = (float)KV[5],        \
              e6 = (float)KV[6], e7 = (float)KV[7];                           \
        const float4 f0a = Pp[6*(R)+0], f0b = Pp[6*(R)+1];                    \
        const float4 f1a = Pp[6*(R)+2], f1b = Pp[6*(R)+3];                    \
        const float4 va  = Pp[6*(R)+4], vb  = Pp[6*(R)+5];                    \
        QTERM(T0, e0, e1, e2, e3, f0a, va)                                    \
        QTERM(T0, e4, e5, e6, e7, f0b, vb)                                    \
        QTERM(T1, e0, e1, e2, e3, f1a, va)                                    \
        QTERM(T1, e4, e5, e6, e7, f1b, vb)                                    \
    }

    for (int gg = 0; gg < 32; gg += 4) {
        const int g = (gg + sb) & 31;          // rotated row-group
        if (gg + 4 < 32) {
            const int gn = (g + 4) & 31;
            kn0 = kp[(long)(gn + 0) * PADK];
            kn1 = kp[(long)(gn + 1) * PADK];
            kn2 = kp[(long)(gn + 2) * PADK];
            kn3 = kp[(long)(gn + 3) * PADK];
        }
        PROW(ka0, g + 0)
        PROW(ka1, g + 1)
        PROW(ka2, g + 2)
        PROW(ka3, g + 3)
        ka0 = kn0; ka1 = kn1; ka2 = kn2; ka3 = kn3;
    }
#undef PROW
#undef QTERM

    float val0 = -2.f * T0;
    float val1 = -2.f * T1;

    // ---- log-softmax over k, no max pass (|val| <= 2*sum|v| ~ 16, safe) ----
    __shared__ float red[8][2];
    const int lane = k & 63, wv = k >> 6;

    float e0 = __builtin_amdgcn_exp2f(val0 * 1.4426950408889634f);
    float e1 = __builtin_amdgcn_exp2f(val1 * 1.4426950408889634f);
    #pragma unroll
    for (int o = 32; o; o >>= 1) {
        e0 += __shfl_xor(e0, o, 64);
        e1 += __shfl_xor(e1, o, 64);
    }
    if (lane == 0) { red[wv][0] = e0; red[wv][1] = e1; }
    __syncthreads();
    float s0 = 0.f, s1 = 0.f;
    #pragma unroll
    for (int w = 0; w < 8; ++w) { s0 += red[w][0]; s1 += red[w][1]; }

    float l0 = __builtin_amdgcn_logf(s0) * 0.6931471805599453f;
    float l1 = __builtin_amdgcn_logf(s1) * 0.6931471805599453f;
    out[((long)b * NQ_ + q0 + 0) * NK_ + k] = val0 - l0;
    out[((long)b * NQ_ + q0 + 1) * NK_ + k] = val1 - l1;
}

extern "C" void kernel_launch(void* const* d_in, const int* in_sizes, int n_in,
                              void* d_out, int out_size, void* d_ws, size_t ws_size,
                              hipStream_t stream)
{
    const float* xq = (const float*)d_in[0];  // (4,256,256)
    const float* xk = (const float*)d_in[1];  // (4,512,256)
    const float* w1 = (const float*)d_in[2];  // (256,256) out,in
    const float* w2 = (const float*)d_in[3];  // (256,256)
    const float* v  = (const float*)d_in[4];  // (1,256)
    float* out = (float*)d_out;

    _Float16* Ebuf = (_Float16*)d_ws;                     // ~1.06MB fp16
    float* Pack = (float*)((char*)d_ws + (size_t)B_ * 32 * PADK * 8 * 2);  // 1.5MB

    gemm_fused<<<dim3(192), 512, 0, stream>>>(xq, xk, w1, w2, v, Ebuf, Pack);
    attn_main<<<dim3(NQ_ / 2, B_), 512, 0, stream>>>(
        (const half8*)Ebuf, Pack, out);
}